// Round 16
// baseline (112.268 us; speedup 1.0000x reference)
//
#include <hip/hip_runtime.h>
#include <math.h>

#define BB 256
#define II 2048
#define CC 10
#define DOUT 16
#define COW 160                 // C*DOUT
#define WELEMS (II*CC*DOUT*8)   // 2,621,440 W elements
#define BT 16                   // b per block
#define LEN 64                  // i per block
#define IW 16                   // i per wave (4 i-quads)
#define NSPLIT (II/LEN)         // 32 p-segments

typedef short  short8v __attribute__((ext_vector_type(8)));
typedef float  f32x4   __attribute__((ext_vector_type(4)));

__device__ __forceinline__ ushort f2bf(float x) {   // RNE f32 -> bf16 bits
    union { float f; unsigned u; } v; v.f = x;
    unsigned r = v.u + 0x7fff + ((v.u >> 16) & 1);
    return (ushort)(r >> 16);
}
__device__ __forceinline__ float bf2f(ushort h) {
    union { unsigned u; float f; } v; v.u = ((unsigned)h) << 16; return v.f;
}
__device__ __forceinline__ short8v pack8(float a0, float a1, float a2, float a3,
                                         float b0, float b1, float b2, float b3) {
    short8v r;
    r[0]=(short)f2bf(a0); r[1]=(short)f2bf(a1); r[2]=(short)f2bf(a2); r[3]=(short)f2bf(a3);
    r[4]=(short)f2bf(b0); r[5]=(short)f2bf(b1); r[6]=(short)f2bf(b2); r[7]=(short)f2bf(b3);
    return r;
}

// ---------------- W f32 -> bf16, once ----------------
__global__ __launch_bounds__(256)
void wcvt(const float* __restrict__ W, ushort* __restrict__ Wb)
{
    const size_t e = ((size_t)blockIdx.x * 256 + threadIdx.x) * 8;
    const float4 x0 = *(const float4*)(W + e);
    const float4 x1 = *(const float4*)(W + e + 4);
    *(short8v*)(Wb + e) = pack8(x0.x, x0.y, x0.z, x0.w, x1.x, x1.y, x1.z, x1.w);
}

// ---------------- unified pass kernel ----------------
// Block: 16 b x 64 i; wave w owns i in [i0+w*16, i0+w*16+16) (4 i-quads).
// Per iq-round, the block's active W (16 i x 10 c x 256B = 40 KB) is bulk-
// staged into LDS (coalesced), so the inner loop's w8 fragment loads are
// ds_read_b128 instead of scattered latency-exposed global loads.
// MODE 0: dense (c_ij uniform; 0.1 applied in squash).
// MODE 1: routing (r11-verified masked-MFMA agreement + register softmax).
template<int MODE>
__global__ __launch_bounds__(256, 3)
void caps_route(const float* __restrict__ u, const ushort* __restrict__ Wb,
                const float* __restrict__ vv, float* __restrict__ p)
{
    __shared__ ushort us[BT * LEN * 8];         // 16 KB (u tile, persists)
    __shared__ union {
        ushort wl[16 * CC * 128];               // 40 KB (W round buffer)
        float  red[4 * CC * 4 * BT * 4];        // 40 KB [w][c][g][bl][r]
    } sm;

    const int tid = threadIdx.x;
    const int l   = tid & 63;
    const int w   = tid >> 6;        // wave id = i-subrange owner
    const int bl  = l & 15;          // b within tile (B/D col)
    const int g   = l >> 4;          // k-group
    const int bbase = blockIdx.y * BT;
    const int b_abs = bbase + bl;
    const int i0    = blockIdx.x * LEN;

    // ---- stage u -> bf16 LDS (coalesced) ----
    for (int e = tid; e < BT * LEN * 2; e += 256) {
        const int rb = e / (LEN * 2), rem = e % (LEN * 2);
        const int i = rem >> 1, dh = (rem & 1) * 4;
        const float4 x = *(const float4*)(u + ((size_t)(bbase + rb) * II + i0 + i) * 8 + dh);
        ushort4 h;
        h.x = f2bf(x.x); h.y = f2bf(x.y); h.z = f2bf(x.z); h.w = f2bf(x.w);
        *(ushort4*)&us[(rb * LEN + (i ^ (rb & 7))) * 8 + dh] = h;
    }

    // ---- v regs: vreg[c][r] = v[b, c, o=4g+r] ----
    float vreg[CC][4];
    if constexpr (MODE >= 1) {
#pragma unroll
        for (int c = 0; c < CC; ++c) {
            const float4 x = *(const float4*)(vv + b_abs * COW + c * DOUT + 4 * g);
            vreg[c][0] = x.x; vreg[c][1] = x.y; vreg[c][2] = x.z; vreg[c][3] = x.w;
        }
    }

    f32x4 acc[CC];
#pragma unroll
    for (int c = 0; c < CC; ++c) acc[c] = (f32x4){0.f, 0.f, 0.f, 0.f};
    const short8v zero8 = {0,0,0,0,0,0,0,0};
    const f32x4   zacc  = (f32x4){0.f, 0.f, 0.f, 0.f};

    __syncthreads();   // us staged; also gates round 0's wl staging

#pragma unroll
    for (int iq = 0; iq < IW / 4; ++iq) {
        // ---- stage this round's W: rows (w*4+j)*10+c  <- Wb[i0+w*16+iq*4+j][c]
        for (int e = tid; e < 16 * CC * 16; e += 256) {
            const int row = e >> 4;          // [0,160)
            const int q   = e & 15;
            const int wj  = row / CC;
            const int c   = row % CC;
            const int i   = i0 + (wj >> 2) * IW + iq * 4 + (wj & 3);
            *(short8v*)&sm.wl[row * 128 + q * 8] =
                *(const short8v*)&Wb[((size_t)i * CC + c) * 128 + q * 8];
        }
        __syncthreads();

        const int iloc = w * IW + iq * 4;        // block-local i base
        const short8v u8 = *(const short8v*)
            &us[(bl * LEN + ((iloc + g) ^ (bl & 7))) * 8];
        const int wrow = (w * 4 + g) * CC;       // this lane's W row block

        if constexpr (MODE == 0) {
            // ---- dense fold only: acc_c += W * u over the i-quad ----
#pragma unroll
            for (int c = 0; c < CC; ++c) {
                const short8v w8 = *(const short8v*)&sm.wl[(wrow + c) * 128 + bl * 8];
                acc[c] = __builtin_amdgcn_mfma_f32_16x16x32_bf16(w8, u8, acc[c], 0, 0, 0);
            }
        } else {
            float uf[8];
#pragma unroll
            for (int e = 0; e < 8; ++e) uf[e] = bf2f((ushort)u8[e]);

            float tk[CC];
            short8v w8r[CC];
            // ---- agreement (r11-verified) ----
#pragma unroll
            for (int c = 0; c < CC; ++c) {
                const short8v w8 = *(const short8v*)&sm.wl[(wrow + c) * 128 + bl * 8];
                w8r[c] = w8;
                f32x4 uh[4];
#pragma unroll
                for (int j = 0; j < 4; ++j)
                    uh[j] = __builtin_amdgcn_mfma_f32_16x16x32_bf16(
                        w8, (g == j) ? u8 : zero8, zacc, 0, 0, 0);
                float d0 = uh[0][0]*vreg[c][0] + uh[0][1]*vreg[c][1]
                         + uh[0][2]*vreg[c][2] + uh[0][3]*vreg[c][3];
                float d1 = uh[1][0]*vreg[c][0] + uh[1][1]*vreg[c][1]
                         + uh[1][2]*vreg[c][2] + uh[1][3]*vreg[c][3];
                float d2 = uh[2][0]*vreg[c][0] + uh[2][1]*vreg[c][1]
                         + uh[2][2]*vreg[c][2] + uh[2][3]*vreg[c][3];
                float d3 = uh[3][0]*vreg[c][0] + uh[3][1]*vreg[c][1]
                         + uh[3][2]*vreg[c][2] + uh[3][3]*vreg[c][3];
                d0 += __shfl_xor(d0, 16); d0 += __shfl_xor(d0, 32);
                d1 += __shfl_xor(d1, 16); d1 += __shfl_xor(d1, 32);
                d2 += __shfl_xor(d2, 16); d2 += __shfl_xor(d2, 32);
                d3 += __shfl_xor(d3, 16); d3 += __shfl_xor(d3, 32);
                float sel = d0;
                sel = (g == 1) ? d1 : sel;
                sel = (g == 2) ? d2 : sel;
                sel = (g == 3) ? d3 : sel;
                tk[c] = sel;               // a[b=bl, i=ig+g, c]
            }

            // ---- softmax over c in regs (|logits| small -> no max-sub) ----
            float s = 0.f;
#pragma unroll
            for (int c = 0; c < CC; ++c) { tk[c] = __expf(tk[c]); s += tk[c]; }
            const float inv = 1.f / s;

            // ---- fold: acc_c += W * (cij .* u), full K over the i-quad ----
#pragma unroll
            for (int c = 0; c < CC; ++c) {
                const float cw = tk[c] * inv;
                const short8v bfB = pack8(cw*uf[0], cw*uf[1], cw*uf[2], cw*uf[3],
                                          cw*uf[4], cw*uf[5], cw*uf[6], cw*uf[7]);
                acc[c] = __builtin_amdgcn_mfma_f32_16x16x32_bf16(w8r[c], bfB, acc[c], 0, 0, 0);
            }
        }
        __syncthreads();   // round's wl reads complete before restage/red
    }

    // ---- cross-wave reduction: 4 waves -> one p segment per block ----
#pragma unroll
    for (int c = 0; c < CC; ++c)
        *(f32x4*)&sm.red[(((w * CC + c) * 4 + g) * BT + bl) * 4] = acc[c];
    __syncthreads();

    float* pp = p + (size_t)blockIdx.x * (BB * COW) + (size_t)b_abs * COW;
    for (int c = w * 3; c < CC && c < w * 3 + 3; ++c) {   // w0:0-2 w1:3-5 w2:6-8 w3:9
        f32x4 sacc = (f32x4){0.f, 0.f, 0.f, 0.f};
#pragma unroll
        for (int ww = 0; ww < 4; ++ww) {
            const f32x4 t = *(const f32x4*)&sm.red[(((ww * CC + c) * 4 + g) * BT + bl) * 4];
            sacc[0] += t[0]; sacc[1] += t[1]; sacc[2] += t[2]; sacc[3] += t[3];
        }
        *(float4*)(pp + c * DOUT + 4 * g) =
            make_float4(sacc[0], sacc[1], sacc[2], sacc[3]);
    }
}

// one wave per (b,c): sum partials over nsplit segs (2 ILP chains), scale,
// squash -> vout; optionally also write vsout = v + vprev (for pass-3's vs).
__global__ __launch_bounds__(64)
void reduce_squash(const float* __restrict__ p, int nsplit, float scale,
                   float* __restrict__ vout, const float* __restrict__ vprev,
                   float* __restrict__ vsout)
{
    const int bc = blockIdx.x;
    const int b = bc / CC, c = bc % CC;
    const int l = threadIdx.x;
    const int o = l & 15, g = l >> 4;
    const float* base = p + (size_t)b * COW + c * DOUT + o;

    float s0 = 0.f, s1 = 0.f;
    for (int sp = g; sp < nsplit; sp += 8)
        s0 += base[(size_t)sp * (BB * COW)];
    for (int sp = g + 4; sp < nsplit; sp += 8)
        s1 += base[(size_t)sp * (BB * COW)];
    float s = s0 + s1;
    s += __shfl_xor(s, 16);
    s += __shfl_xor(s, 32);
    s *= scale;
    float sq = s * s;
    sq += __shfl_xor(sq, 1);
    sq += __shfl_xor(sq, 2);
    sq += __shfl_xor(sq, 4);
    sq += __shfl_xor(sq, 8);
    const float sc = (sq / (1.f + sq)) * rsqrtf(sq + 1e-9f);
    if (l < 16) {
        const int idx = b * COW + c * DOUT + o;
        const float v = s * sc;
        vout[idx] = v;
        if (vsout) vsout[idx] = v + vprev[idx];
    }
}

extern "C" void kernel_launch(void* const* d_in, const int* in_sizes, int n_in,
                              void* d_out, int out_size, void* d_ws, size_t ws_size,
                              hipStream_t stream)
{
    const float* u = (const float*)d_in[0];   // [256,2048,8]
    const float* W = (const float*)d_in[1];   // [2048,10,16,8]
    float* out = (float*)d_out;               // [256,10,16]

    const size_t SEG = (size_t)BB * COW;      // 40960 floats
    float*  v0 = (float*)d_ws;
    float*  v1 = v0 + SEG;
    float*  vs = v1 + SEG;
    ushort* Wb = (ushort*)(vs + SEG);         // 5.25 MB
    float*  p  = (float*)(Wb + WELEMS);       // NSPLIT * 160KB = 5.25 MB

    dim3 grid(NSPLIT, BB / BT);               // (32, 16) = 512 blocks

    wcvt<<<WELEMS / (256 * 8), 256, 0, stream>>>(W, Wb);
    caps_route<0><<<grid, 256, 0, stream>>>(u, Wb, nullptr, p);
    reduce_squash<<<BB * CC, 64, 0, stream>>>(p, NSPLIT, 0.1f, v0, nullptr, nullptr);
    caps_route<1><<<grid, 256, 0, stream>>>(u, Wb, v0, p);
    reduce_squash<<<BB * CC, 64, 0, stream>>>(p, NSPLIT, 1.f, v1, v0, vs);
    caps_route<1><<<grid, 256, 0, stream>>>(u, Wb, vs, p);
    reduce_squash<<<BB * CC, 64, 0, stream>>>(p, NSPLIT, 1.f, out, nullptr, nullptr);
}

// Round 17
// 82.024 us; speedup vs baseline: 1.3687x; 1.3687x over previous
//
#include <hip/hip_runtime.h>
#include <math.h>

#define BB 256
#define II 2048
#define CC 10
#define DOUT 16
#define COW 160                 // C*DOUT
#define WELEMS (II*CC*DOUT*8)   // 2,621,440 W elements
#define BT 16                   // b per block
#define LEN 64                  // i per block
#define IW 16                   // i per wave (4 i-quads)
#define NSPLIT (II/LEN)         // 32 p-segments

typedef short  short8v __attribute__((ext_vector_type(8)));
typedef float  f32x4   __attribute__((ext_vector_type(4)));

__device__ __forceinline__ ushort f2bf(float x) {   // RNE f32 -> bf16 bits
    union { float f; unsigned u; } v; v.f = x;
    unsigned r = v.u + 0x7fff + ((v.u >> 16) & 1);
    return (ushort)(r >> 16);
}
__device__ __forceinline__ float bf2f(ushort h) {
    union { unsigned u; float f; } v; v.u = ((unsigned)h) << 16; return v.f;
}
__device__ __forceinline__ short8v pack8(float a0, float a1, float a2, float a3,
                                         float b0, float b1, float b2, float b3) {
    short8v r;
    r[0]=(short)f2bf(a0); r[1]=(short)f2bf(a1); r[2]=(short)f2bf(a2); r[3]=(short)f2bf(a3);
    r[4]=(short)f2bf(b0); r[5]=(short)f2bf(b1); r[6]=(short)f2bf(b2); r[7]=(short)f2bf(b3);
    return r;
}

// ---------------- W f32 -> bf16, once ----------------
__global__ __launch_bounds__(256)
void wcvt(const float* __restrict__ W, ushort* __restrict__ Wb)
{
    const size_t e = ((size_t)blockIdx.x * 256 + threadIdx.x) * 8;
    const float4 x0 = *(const float4*)(W + e);
    const float4 x1 = *(const float4*)(W + e + 4);
    *(short8v*)(Wb + e) = pack8(x0.x, x0.y, x0.z, x0.w, x1.x, x1.y, x1.z, x1.w);
}

// ---------------- unified pass kernel (r11-verified body) ----------------
// Block: 16 b x 64 i; wave w owns i in [i0+w*16, i0+w*16+16) (4 i-quads).
// MODE 0: dense (c_ij uniform; 0.1 applied in squash).
// MODE 1: routing with v from `vv` (pass1: v0; pass2: vs = v0+v1).
// launch_bounds (256,2): grid (512 blocks) caps residency at 2 blocks/CU
// anyway, so let the register allocator use up to ~256 VGPR for deep
// pipelining of the 10 independent c-iterations and across iq's.
template<int MODE>
__global__ __launch_bounds__(256, 2)
void caps_route(const float* __restrict__ u, const ushort* __restrict__ Wb,
                const float* __restrict__ vv, float* __restrict__ p)
{
    __shared__ union {
        ushort us[BT * LEN * 8];                // 16 KB (u tile, bf16)
        float  red[4 * CC * 4 * BT * 4];        // 40 KB [w][c][g][bl][r]
    } sm;

    const int tid = threadIdx.x;
    const int l   = tid & 63;
    const int w   = tid >> 6;        // wave id = i-subrange owner
    const int bl  = l & 15;          // b within tile (B/D col); also A-row o
    const int g   = l >> 4;          // k-group
    const int bbase = blockIdx.y * BT;
    const int b_abs = bbase + bl;
    const int i0    = blockIdx.x * LEN;

    // ---- stage u -> bf16 LDS (coalesced) ----
    for (int e = tid; e < BT * LEN * 2; e += 256) {
        const int rb = e / (LEN * 2), rem = e % (LEN * 2);
        const int i = rem >> 1, dh = (rem & 1) * 4;
        const float4 x = *(const float4*)(u + ((size_t)(bbase + rb) * II + i0 + i) * 8 + dh);
        ushort4 h;
        h.x = f2bf(x.x); h.y = f2bf(x.y); h.z = f2bf(x.z); h.w = f2bf(x.w);
        *(ushort4*)&sm.us[(rb * LEN + (i ^ (rb & 7))) * 8 + dh] = h;
    }

    // ---- v regs: vreg[c][r] = v[b, c, o=4g+r] ----
    float vreg[CC][4];
    if constexpr (MODE >= 1) {
#pragma unroll
        for (int c = 0; c < CC; ++c) {
            const float4 x = *(const float4*)(vv + b_abs * COW + c * DOUT + 4 * g);
            vreg[c][0] = x.x; vreg[c][1] = x.y; vreg[c][2] = x.z; vreg[c][3] = x.w;
        }
    }

    f32x4 acc[CC];
#pragma unroll
    for (int c = 0; c < CC; ++c) acc[c] = (f32x4){0.f, 0.f, 0.f, 0.f};
    const short8v zero8 = {0,0,0,0,0,0,0,0};
    const f32x4   zacc  = (f32x4){0.f, 0.f, 0.f, 0.f};

    __syncthreads();

#pragma unroll
    for (int iq = 0; iq < IW / 4; ++iq) {
        const int ig   = i0 + w * IW + iq * 4;   // global i base of this quad
        const int iloc = w * IW + iq * 4;        // block-local
        const short8v u8 = *(const short8v*)
            &sm.us[(bl * LEN + ((iloc + g) ^ (bl & 7))) * 8];

        if constexpr (MODE == 0) {
            // ---- dense fold only: acc_c += W * u over the i-quad ----
#pragma unroll
            for (int c = 0; c < CC; ++c) {
                const short8v w8 = *(const short8v*)
                    &Wb[((size_t)(ig + g) * CC + c) * 128 + bl * 8];
                acc[c] = __builtin_amdgcn_mfma_f32_16x16x32_bf16(w8, u8, acc[c], 0, 0, 0);
            }
        } else {
            float uf[8];
#pragma unroll
            for (int e = 0; e < 8; ++e) uf[e] = bf2f((ushort)u8[e]);

            float tk[CC];
            short8v w8r[CC];
            // ---- agreement (round-8-validated) ----
#pragma unroll
            for (int c = 0; c < CC; ++c) {
                const short8v w8 = *(const short8v*)
                    &Wb[((size_t)(ig + g) * CC + c) * 128 + bl * 8];
                w8r[c] = w8;
                f32x4 uh[4];
#pragma unroll
                for (int j = 0; j < 4; ++j)
                    uh[j] = __builtin_amdgcn_mfma_f32_16x16x32_bf16(
                        w8, (g == j) ? u8 : zero8, zacc, 0, 0, 0);
                float d0 = uh[0][0]*vreg[c][0] + uh[0][1]*vreg[c][1]
                         + uh[0][2]*vreg[c][2] + uh[0][3]*vreg[c][3];
                float d1 = uh[1][0]*vreg[c][0] + uh[1][1]*vreg[c][1]
                         + uh[1][2]*vreg[c][2] + uh[1][3]*vreg[c][3];
                float d2 = uh[2][0]*vreg[c][0] + uh[2][1]*vreg[c][1]
                         + uh[2][2]*vreg[c][2] + uh[2][3]*vreg[c][3];
                float d3 = uh[3][0]*vreg[c][0] + uh[3][1]*vreg[c][1]
                         + uh[3][2]*vreg[c][2] + uh[3][3]*vreg[c][3];
                d0 += __shfl_xor(d0, 16); d0 += __shfl_xor(d0, 32);
                d1 += __shfl_xor(d1, 16); d1 += __shfl_xor(d1, 32);
                d2 += __shfl_xor(d2, 16); d2 += __shfl_xor(d2, 32);
                d3 += __shfl_xor(d3, 16); d3 += __shfl_xor(d3, 32);
                float sel = d0;
                sel = (g == 1) ? d1 : sel;
                sel = (g == 2) ? d2 : sel;
                sel = (g == 3) ? d3 : sel;
                tk[c] = sel;               // a[b=bl, i=ig+g, c]
            }

            // ---- softmax over c in regs (|logits| small -> no max-sub) ----
            float s = 0.f;
#pragma unroll
            for (int c = 0; c < CC; ++c) { tk[c] = __expf(tk[c]); s += tk[c]; }
            const float inv = 1.f / s;

            // ---- fold: acc_c += W * (cij .* u), full K over the i-quad ----
#pragma unroll
            for (int c = 0; c < CC; ++c) {
                const float cw = tk[c] * inv;
                const short8v bfB = pack8(cw*uf[0], cw*uf[1], cw*uf[2], cw*uf[3],
                                          cw*uf[4], cw*uf[5], cw*uf[6], cw*uf[7]);
                acc[c] = __builtin_amdgcn_mfma_f32_16x16x32_bf16(w8r[c], bfB, acc[c], 0, 0, 0);
            }
        }
    }

    // ---- cross-wave reduction: 4 waves -> one p segment per block ----
    __syncthreads();                       // all waves done with sm.us
#pragma unroll
    for (int c = 0; c < CC; ++c)
        *(f32x4*)&sm.red[(((w * CC + c) * 4 + g) * BT + bl) * 4] = acc[c];
    __syncthreads();

    float* pp = p + (size_t)blockIdx.x * (BB * COW) + (size_t)b_abs * COW;
    for (int c = w * 3; c < CC && c < w * 3 + 3; ++c) {   // w0:0-2 w1:3-5 w2:6-8 w3:9
        f32x4 sacc = (f32x4){0.f, 0.f, 0.f, 0.f};
#pragma unroll
        for (int ww = 0; ww < 4; ++ww) {
            const f32x4 t = *(const f32x4*)&sm.red[(((ww * CC + c) * 4 + g) * BT + bl) * 4];
            sacc[0] += t[0]; sacc[1] += t[1]; sacc[2] += t[2]; sacc[3] += t[3];
        }
        *(float4*)(pp + c * DOUT + 4 * g) =
            make_float4(sacc[0], sacc[1], sacc[2], sacc[3]);
    }
}

// one wave per (b,c): sum partials over nsplit segs (2 ILP chains), scale,
// squash -> vout; optionally also write vsout = v + vprev (for pass-3's vs).
__global__ __launch_bounds__(64)
void reduce_squash(const float* __restrict__ p, int nsplit, float scale,
                   float* __restrict__ vout, const float* __restrict__ vprev,
                   float* __restrict__ vsout)
{
    const int bc = blockIdx.x;
    const int b = bc / CC, c = bc % CC;
    const int l = threadIdx.x;
    const int o = l & 15, g = l >> 4;
    const float* base = p + (size_t)b * COW + c * DOUT + o;

    float s0 = 0.f, s1 = 0.f;
    for (int sp = g; sp < nsplit; sp += 8)
        s0 += base[(size_t)sp * (BB * COW)];
    for (int sp = g + 4; sp < nsplit; sp += 8)
        s1 += base[(size_t)sp * (BB * COW)];
    float s = s0 + s1;
    s += __shfl_xor(s, 16);
    s += __shfl_xor(s, 32);
    s *= scale;
    float sq = s * s;
    sq += __shfl_xor(sq, 1);
    sq += __shfl_xor(sq, 2);
    sq += __shfl_xor(sq, 4);
    sq += __shfl_xor(sq, 8);
    const float sc = (sq / (1.f + sq)) * rsqrtf(sq + 1e-9f);
    if (l < 16) {
        const int idx = b * COW + c * DOUT + o;
        const float v = s * sc;
        vout[idx] = v;
        if (vsout) vsout[idx] = v + vprev[idx];
    }
}

extern "C" void kernel_launch(void* const* d_in, const int* in_sizes, int n_in,
                              void* d_out, int out_size, void* d_ws, size_t ws_size,
                              hipStream_t stream)
{
    const float* u = (const float*)d_in[0];   // [256,2048,8]
    const float* W = (const float*)d_in[1];   // [2048,10,16,8]
    float* out = (float*)d_out;               // [256,10,16]

    const size_t SEG = (size_t)BB * COW;      // 40960 floats
    float*  v0 = (float*)d_ws;
    float*  v1 = v0 + SEG;
    float*  vs = v1 + SEG;
    ushort* Wb = (ushort*)(vs + SEG);         // 5.25 MB
    float*  p  = (float*)(Wb + WELEMS);       // NSPLIT * 160KB = 5.25 MB

    dim3 grid(NSPLIT, BB / BT);               // (32, 16) = 512 blocks

    wcvt<<<WELEMS / (256 * 8), 256, 0, stream>>>(W, Wb);
    caps_route<0><<<grid, 256, 0, stream>>>(u, Wb, nullptr, p);
    reduce_squash<<<BB * CC, 64, 0, stream>>>(p, NSPLIT, 0.1f, v0, nullptr, nullptr);
    caps_route<1><<<grid, 256, 0, stream>>>(u, Wb, v0, p);
    reduce_squash<<<BB * CC, 64, 0, stream>>>(p, NSPLIT, 1.f, v1, v0, vs);
    caps_route<1><<<grid, 256, 0, stream>>>(u, Wb, vs, p);
    reduce_squash<<<BB * CC, 64, 0, stream>>>(p, NSPLIT, 1.f, out, nullptr, nullptr);
}